// Round 4
// baseline (465.253 us; speedup 1.0000x reference)
//
#include <hip/hip_runtime.h>
#include <math.h>

// Problem constants (fixed by the reference):
#define NEXP 4               // n
#define STREAM 4096          // N*C
#define NOUT 24              // n*n + 2n
#define NTOK 16384           // B*L
#define SK_ITERS 20

// Tiling:
#define T_PER_BLOCK 8        // tokens per block (phi reuse factor)
#define CHUNK 512            // k-values staged per chunk
#define NCHUNK (STREAM / CHUNK)   // 8

// ---------------------------------------------------------------------------
// Kernel A: phiT[j][k] = scale[k] * phi[k][j]   (24 x 4096, transposed+scaled)
// ---------------------------------------------------------------------------
__global__ __launch_bounds__(256) void k_transpose_scale(
    const float* __restrict__ phi, const float* __restrict__ scale,
    float* __restrict__ phiT) {
  int flat = blockIdx.x * 256 + threadIdx.x;   // 0..98303, flat = k*24 + j
  int k = flat / NOUT;
  int j = flat - k * NOUT;
  phiT[j * STREAM + k] = phi[flat] * scale[k];
}

// ---------------------------------------------------------------------------
// One chunk step (double-buffered):
//   barrier -> issue prefetch loads (ch+1) -> FMA compute on bufC -> ds_write
//   prefetch to bufN. Loads are issued AFTER the barrier so the compiler's
//   vmcnt(0)-before-s_barrier drain applies to the PREVIOUS chunk's loads
//   (already complete); the new loads' ~900-cycle HBM latency hides under the
//   ~768-cycle FMA body. FP order is bitwise-identical to the verified kernel.
// ---------------------------------------------------------------------------
__device__ __forceinline__ void chunk_step(
    int ch, int w, int lane, int rowA, int rowB,
    const float4* __restrict__ x4, const float4* __restrict__ phiT4,
    const float* bufC, float* bufN,
    float (&acc)[T_PER_BLOCK][6], float& ssq0, float& ssq1) {
  float4 a0, a1, b0, b1;
  const bool pref = (ch + 1 < NCHUNK);   // uniform branch

  __syncthreads();   // bufC stores from previous step visible to all waves

  if (pref) {
    int off = (ch + 1) * (CHUNK / 4);
    a0 = x4[rowA + off + lane];
    a1 = x4[rowA + off + 64 + lane];
    b0 = x4[rowB + off + lane];
    b1 = x4[rowB + off + 64 + lane];
  }

  const float4* l4 = (const float4*)bufC;
  const int pbase = (6 * w) * (STREAM / 4) + ch * (CHUNK / 4);
#pragma unroll
  for (int i = 0; i < 2; i++) {
    int k4 = i * 64 + lane;
    float4 p[6];
#pragma unroll
    for (int jj = 0; jj < 6; jj++)
      p[jj] = phiT4[pbase + jj * (STREAM / 4) + k4];
#pragma unroll
    for (int t = 0; t < T_PER_BLOCK; t++) {
      float4 xv = l4[t * (CHUNK / 4) + k4];
#pragma unroll
      for (int jj = 0; jj < 6; jj++) {
        float a = acc[t][jj];
        a = fmaf(xv.x, p[jj].x, a);
        a = fmaf(xv.y, p[jj].y, a);
        a = fmaf(xv.z, p[jj].z, a);
        a = fmaf(xv.w, p[jj].w, a);
        acc[t][jj] = a;
      }
    }
  }

  if (pref) {
    float4* n4 = (float4*)bufN;
    n4[(2 * w) * (CHUNK / 4) + lane]          = a0;
    n4[(2 * w) * (CHUNK / 4) + 64 + lane]     = a1;
    n4[(2 * w + 1) * (CHUNK / 4) + lane]      = b0;
    n4[(2 * w + 1) * (CHUNK / 4) + 64 + lane] = b1;
    // sumsq on raw x, same accumulation order as the verified version
    ssq0 += a0.x * a0.x + a0.y * a0.y + a0.z * a0.z + a0.w * a0.w;
    ssq0 += a1.x * a1.x + a1.y * a1.y + a1.z * a1.z + a1.w * a1.w;
    ssq1 += b0.x * b0.x + b0.y * b0.y + b0.z * b0.z + b0.w * b0.w;
    ssq1 += b1.x * b1.x + b1.y * b1.y + b1.z * b1.z + b1.w * b1.w;
  }
}

// ---------------------------------------------------------------------------
// Fused kernel: RMSNorm-dot (matvec) + heads + Sinkhorn, m stays in LDS.
//   block = 256 threads (4 waves), 8 tokens per block.
//   wave w stages tokens 2w,2w+1; computes j-range [6w,6w+6) for all 8 tokens.
//   Tail: first 128 threads run heads + SK (16 lanes per token).
// ---------------------------------------------------------------------------
__global__ __launch_bounds__(256) void k_fused(
    const float* __restrict__ x, const float* __restrict__ phiT,
    const float* __restrict__ bias,
    const float* __restrict__ a_pre_p, const float* __restrict__ a_post_p,
    const float* __restrict__ a_res_p, float* __restrict__ out) {
  __shared__ float lds_x0[T_PER_BLOCK * CHUNK];   // 16 KB
  __shared__ float lds_x1[T_PER_BLOCK * CHUNK];   // 16 KB (double buffer)
  __shared__ float lds_m[T_PER_BLOCK * NOUT];     // 192 floats
  __shared__ float lds_inv[T_PER_BLOCK];          // 1/rms per token

  const int tid  = threadIdx.x;
  const int w    = tid >> 6;
  const int lane = tid & 63;
  const int tok0 = blockIdx.x * T_PER_BLOCK;

  const float4* x4    = (const float4*)x;
  const float4* phiT4 = (const float4*)phiT;

  float acc[T_PER_BLOCK][6];
#pragma unroll
  for (int t = 0; t < T_PER_BLOCK; t++)
#pragma unroll
    for (int jj = 0; jj < 6; jj++) acc[t][jj] = 0.0f;
  float ssq0 = 0.0f, ssq1 = 0.0f;

  const int rowA = (tok0 + 2 * w) * (STREAM / 4);
  const int rowB = rowA + (STREAM / 4);

  // ---- prologue: stage chunk 0 into buffer 0 ----
  {
    float4 a0 = x4[rowA + lane];
    float4 a1 = x4[rowA + 64 + lane];
    float4 b0 = x4[rowB + lane];
    float4 b1 = x4[rowB + 64 + lane];
    float4* n4 = (float4*)lds_x0;
    n4[(2 * w) * (CHUNK / 4) + lane]          = a0;
    n4[(2 * w) * (CHUNK / 4) + 64 + lane]     = a1;
    n4[(2 * w + 1) * (CHUNK / 4) + lane]      = b0;
    n4[(2 * w + 1) * (CHUNK / 4) + 64 + lane] = b1;
    ssq0 += a0.x * a0.x + a0.y * a0.y + a0.z * a0.z + a0.w * a0.w;
    ssq0 += a1.x * a1.x + a1.y * a1.y + a1.z * a1.z + a1.w * a1.w;
    ssq1 += b0.x * b0.x + b0.y * b0.y + b0.z * b0.z + b0.w * b0.w;
    ssq1 += b1.x * b1.x + b1.y * b1.y + b1.z * b1.z + b1.w * b1.w;
  }

  // ---- main loop: ping-pong buffers, one barrier per chunk ----
  for (int ch = 0; ch < NCHUNK; ch += 2) {
    chunk_step(ch,     w, lane, rowA, rowB, x4, phiT4, lds_x0, lds_x1,
               acc, ssq0, ssq1);
    chunk_step(ch + 1, w, lane, rowA, rowB, x4, phiT4, lds_x1, lds_x0,
               acc, ssq0, ssq1);
  }

  // ---- wave-reduce sumsq (tokens 2w, 2w+1) ----
#pragma unroll
  for (int d = 1; d < 64; d <<= 1) {
    ssq0 += __shfl_xor(ssq0, d, 64);
    ssq1 += __shfl_xor(ssq1, d, 64);
  }
  if (lane == 0) {
    lds_inv[2 * w]     = 1.0f / sqrtf(ssq0 * (1.0f / STREAM) + 1e-20f);
    lds_inv[2 * w + 1] = 1.0f / sqrtf(ssq1 * (1.0f / STREAM) + 1e-20f);
  }

  // ---- wave-reduce the 48 accumulators (butterfly; all lanes get totals) ----
#pragma unroll
  for (int d = 1; d < 64; d <<= 1) {
#pragma unroll
    for (int t = 0; t < T_PER_BLOCK; t++)
#pragma unroll
      for (int jj = 0; jj < 6; jj++)
        acc[t][jj] += __shfl_xor(acc[t][jj], d, 64);
  }
  __syncthreads();   // lds_inv visible to all waves

  // ---- write m into LDS: lane t*6+jj holds token t, column j=6w+jj ----
#pragma unroll
  for (int t = 0; t < T_PER_BLOCK; t++) {
    float inv = lds_inv[t];
#pragma unroll
    for (int jj = 0; jj < 6; jj++) {
      if (lane == t * 6 + jj) {
        int j = 6 * w + jj;
        lds_m[t * NOUT + j] = acc[t][jj] * inv + bias[j];
      }
    }
  }
  __syncthreads();   // lds_m visible

  // ---- heads + Sinkhorn tail: 16 lanes per token, first 2 waves only ----
  if (tid < T_PER_BLOCK * 16) {
    int t = tid >> 4;
    int e = tid & 15;            // r*4 + c
    int tok = tok0 + t;

    const float a_res  = *a_res_p;
    const float a_pre  = *a_pre_p;
    const float a_post = *a_post_p;

    float M = expf(a_res * lds_m[t * NOUT + 2 * NEXP + e]);
#pragma unroll 1
    for (int it = 0; it < SK_ITERS; it++) {
      float rs = M + __shfl_xor(M, 1, 64);
      rs += __shfl_xor(rs, 2, 64);
      M = M / (rs + 1e-12f);
      float cs = M + __shfl_xor(M, 4, 64);
      cs += __shfl_xor(cs, 8, 64);
      M = M / (cs + 1e-12f);
    }
    out[2 * NTOK * NEXP + tok * 16 + e] = M;   // h_res at offset 131072

    if (e < NEXP) {
      float z = a_pre * lds_m[t * NOUT + e];
      out[tok * NEXP + e] = 1.0f / (1.0f + expf(-z));
    } else if (e < 2 * NEXP) {
      int j = e - NEXP;
      float z = a_post * lds_m[t * NOUT + NEXP + j];
      out[NTOK * NEXP + tok * NEXP + j] = 2.0f / (1.0f + expf(-z));
    }
  }
}

// ---------------------------------------------------------------------------
extern "C" void kernel_launch(void* const* d_in, const int* in_sizes, int n_in,
                              void* d_out, int out_size, void* d_ws, size_t ws_size,
                              hipStream_t stream) {
  const float* x      = (const float*)d_in[0];
  const float* scale  = (const float*)d_in[1];
  const float* phi    = (const float*)d_in[2];
  const float* bias   = (const float*)d_in[3];
  const float* a_pre  = (const float*)d_in[4];
  const float* a_post = (const float*)d_in[5];
  const float* a_res  = (const float*)d_in[6];
  float* out = (float*)d_out;

  float* phiT = (float*)d_ws;   // 24*4096 = 98304 floats

  k_transpose_scale<<<(NOUT * STREAM) / 256, 256, 0, stream>>>(phi, scale, phiT);
  k_fused<<<NTOK / T_PER_BLOCK, 256, 0, stream>>>(x, phiT, bias, a_pre, a_post,
                                                  a_res, out);
}